// Round 1
// baseline (253.939 us; speedup 1.0000x reference)
//
#include <hip/hip_runtime.h>

constexpr int HW = 1024 * 1024;
constexpr int NB = 16;
constexpr float EPS = 1e-6f;
constexpr int BLOCKS_PER_BATCH = 64;   // 1024 blocks total -> 4/CU
constexpr int THREADS = 256;

// Per-batch partial sums: ws[b*4 + {0,1,2,3}] = {Sp, Spp, St, Stp}
__global__ __launch_bounds__(THREADS) void dice_partial(
        const float* __restrict__ logits,
        const int*   __restrict__ labels,
        float*       __restrict__ ws) {
    const int b   = blockIdx.x >> 6;        // / BLOCKS_PER_BATCH
    const int blk = blockIdx.x & 63;        // % BLOCKS_PER_BATCH

    const float4* __restrict__ L0 = reinterpret_cast<const float4*>(logits + (size_t)b * 2 * HW);
    const float4* __restrict__ L1 = reinterpret_cast<const float4*>(logits + (size_t)b * 2 * HW + HW);
    const int4*   __restrict__ LB = reinterpret_cast<const int4*>(labels + (size_t)b * HW);

    constexpr int NVEC   = HW / 4;                      // 262144 float4 per batch
    constexpr int STRIDE = BLOCKS_PER_BATCH * THREADS;  // 16384

    float sp = 0.f, spp = 0.f, st = 0.f, stp = 0.f;

    for (int i = blk * THREADS + threadIdx.x; i < NVEC; i += STRIDE) {
        float4 a = L0[i];   // class-0 logits
        float4 c = L1[i];   // class-1 logits
        int4   t = LB[i];   // labels in {0,1}

        // p1 = sigmoid(l1 - l0) = 1 / (1 + exp(l0 - l1))
        float p, tf;
        p = 1.f / (1.f + __expf(a.x - c.x)); tf = (float)t.x;
        sp += p; spp = fmaf(p, p, spp); st += tf; stp = fmaf(tf, p, stp);
        p = 1.f / (1.f + __expf(a.y - c.y)); tf = (float)t.y;
        sp += p; spp = fmaf(p, p, spp); st += tf; stp = fmaf(tf, p, stp);
        p = 1.f / (1.f + __expf(a.z - c.z)); tf = (float)t.z;
        sp += p; spp = fmaf(p, p, spp); st += tf; stp = fmaf(tf, p, stp);
        p = 1.f / (1.f + __expf(a.w - c.w)); tf = (float)t.w;
        sp += p; spp = fmaf(p, p, spp); st += tf; stp = fmaf(tf, p, stp);
    }

    // wave-64 shuffle reduction
    #pragma unroll
    for (int off = 32; off > 0; off >>= 1) {
        sp  += __shfl_down(sp,  off);
        spp += __shfl_down(spp, off);
        st  += __shfl_down(st,  off);
        stp += __shfl_down(stp, off);
    }

    __shared__ float red[4][4];   // [wave][component]
    const int wave = threadIdx.x >> 6;
    const int lane = threadIdx.x & 63;
    if (lane == 0) {
        red[wave][0] = sp; red[wave][1] = spp; red[wave][2] = st; red[wave][3] = stp;
    }
    __syncthreads();
    if (threadIdx.x == 0) {
        float a0 = 0.f, a1 = 0.f, a2 = 0.f, a3 = 0.f;
        #pragma unroll
        for (int w = 0; w < 4; ++w) {
            a0 += red[w][0]; a1 += red[w][1]; a2 += red[w][2]; a3 += red[w][3];
        }
        atomicAdd(&ws[b * 4 + 0], a0);
        atomicAdd(&ws[b * 4 + 1], a1);
        atomicAdd(&ws[b * 4 + 2], a2);
        atomicAdd(&ws[b * 4 + 3], a3);
    }
}

__global__ void dice_final(const float* __restrict__ ws, float* __restrict__ out) {
    float local = 0.f;
    const int b = threadIdx.x;
    if (b < NB) {
        const float Sp  = ws[b * 4 + 0];
        const float Spp = ws[b * 4 + 1];
        const float St  = ws[b * 4 + 2];
        const float Stp = ws[b * 4 + 3];
        const float N = (float)HW;

        const float num1 = 2.f * Stp;
        const float den1 = Spp + St;
        const float num0 = 2.f * (N - St - Sp + Stp);
        const float den0 = (N - 2.f * Sp + Spp) + (N - St);

        local = num0 / (den0 + EPS) + num1 / (den1 + EPS);
    }
    #pragma unroll
    for (int off = 32; off > 0; off >>= 1) local += __shfl_down(local, off);
    if (threadIdx.x == 0) out[0] = 1.f - local / 32.f;
}

extern "C" void kernel_launch(void* const* d_in, const int* in_sizes, int n_in,
                              void* d_out, int out_size, void* d_ws, size_t ws_size,
                              hipStream_t stream) {
    const float* logits = (const float*)d_in[0];
    const int*   labels = (const int*)d_in[1];
    float* out = (float*)d_out;
    float* ws  = (float*)d_ws;

    hipMemsetAsync(ws, 0, NB * 4 * sizeof(float), stream);
    dice_partial<<<NB * BLOCKS_PER_BATCH, THREADS, 0, stream>>>(logits, labels, ws);
    dice_final<<<1, 64, 0, stream>>>(ws, out);
}

// Round 2
// 251.457 us; speedup vs baseline: 1.0099x; 1.0099x over previous
//
#include <hip/hip_runtime.h>

constexpr int HW = 1024 * 1024;
constexpr int NB = 16;
constexpr float EPS = 1e-6f;
constexpr int BLOCKS_PER_BATCH = 128;  // 2048 blocks total -> 8 blocks/CU
constexpr int THREADS = 256;
constexpr int NVEC    = HW / 4;                      // 262144 float4 per batch
constexpr int STRIDE  = BLOCKS_PER_BATCH * THREADS;  // 32768
constexpr int ITERS   = NVEC / STRIDE;               // 8
constexpr int U       = 4;                           // load-batch width
constexpr int OUTER   = ITERS / U;                   // 2

// Per-batch partial sums: ws[b*4 + {0,1,2,3}] = {Sp, Spp, St, Stp}
__global__ __launch_bounds__(THREADS, 8) void dice_partial(
        const float* __restrict__ logits,
        const int*   __restrict__ labels,
        float*       __restrict__ ws) {
    const int b   = blockIdx.x >> 7;         // / BLOCKS_PER_BATCH
    const int blk = blockIdx.x & 127;        // % BLOCKS_PER_BATCH

    const float4* __restrict__ L0 = reinterpret_cast<const float4*>(logits + (size_t)b * 2 * HW);
    const float4* __restrict__ L1 = reinterpret_cast<const float4*>(logits + (size_t)b * 2 * HW + HW);
    const int4*   __restrict__ LB = reinterpret_cast<const int4*>(labels + (size_t)b * HW);

    const int base = blk * THREADS + threadIdx.x;

    float sp = 0.f, spp = 0.f, st = 0.f, stp = 0.f;

    #pragma unroll
    for (int o = 0; o < OUTER; ++o) {
        float4 a[U], c[U];
        int4   t[U];
        // Issue all 12 loads of this window before any use -> 12 loads in flight.
        #pragma unroll
        for (int u = 0; u < U; ++u) {
            const int i = base + (o * U + u) * STRIDE;
            a[u] = L0[i];
            c[u] = L1[i];
            t[u] = LB[i];
        }
        #pragma unroll
        for (int u = 0; u < U; ++u) {
            float p, tf;
            p = 1.f / (1.f + __expf(a[u].x - c[u].x)); tf = (float)t[u].x;
            sp += p; spp = fmaf(p, p, spp); st += tf; stp = fmaf(tf, p, stp);
            p = 1.f / (1.f + __expf(a[u].y - c[u].y)); tf = (float)t[u].y;
            sp += p; spp = fmaf(p, p, spp); st += tf; stp = fmaf(tf, p, stp);
            p = 1.f / (1.f + __expf(a[u].z - c[u].z)); tf = (float)t[u].z;
            sp += p; spp = fmaf(p, p, spp); st += tf; stp = fmaf(tf, p, stp);
            p = 1.f / (1.f + __expf(a[u].w - c[u].w)); tf = (float)t[u].w;
            sp += p; spp = fmaf(p, p, spp); st += tf; stp = fmaf(tf, p, stp);
        }
    }

    // wave-64 shuffle reduction
    #pragma unroll
    for (int off = 32; off > 0; off >>= 1) {
        sp  += __shfl_down(sp,  off);
        spp += __shfl_down(spp, off);
        st  += __shfl_down(st,  off);
        stp += __shfl_down(stp, off);
    }

    __shared__ float red[4][4];   // [wave][component]
    const int wave = threadIdx.x >> 6;
    const int lane = threadIdx.x & 63;
    if (lane == 0) {
        red[wave][0] = sp; red[wave][1] = spp; red[wave][2] = st; red[wave][3] = stp;
    }
    __syncthreads();
    if (threadIdx.x == 0) {
        float a0 = 0.f, a1 = 0.f, a2 = 0.f, a3 = 0.f;
        #pragma unroll
        for (int w = 0; w < 4; ++w) {
            a0 += red[w][0]; a1 += red[w][1]; a2 += red[w][2]; a3 += red[w][3];
        }
        atomicAdd(&ws[b * 4 + 0], a0);
        atomicAdd(&ws[b * 4 + 1], a1);
        atomicAdd(&ws[b * 4 + 2], a2);
        atomicAdd(&ws[b * 4 + 3], a3);
    }
}

__global__ void dice_final(const float* __restrict__ ws, float* __restrict__ out) {
    float local = 0.f;
    const int b = threadIdx.x;
    if (b < NB) {
        const float Sp  = ws[b * 4 + 0];
        const float Spp = ws[b * 4 + 1];
        const float St  = ws[b * 4 + 2];
        const float Stp = ws[b * 4 + 3];
        const float N = (float)HW;

        const float num1 = 2.f * Stp;
        const float den1 = Spp + St;
        const float num0 = 2.f * (N - St - Sp + Stp);
        const float den0 = (N - 2.f * Sp + Spp) + (N - St);

        local = num0 / (den0 + EPS) + num1 / (den1 + EPS);
    }
    #pragma unroll
    for (int off = 32; off > 0; off >>= 1) local += __shfl_down(local, off);
    if (threadIdx.x == 0) out[0] = 1.f - local / 32.f;
}

extern "C" void kernel_launch(void* const* d_in, const int* in_sizes, int n_in,
                              void* d_out, int out_size, void* d_ws, size_t ws_size,
                              hipStream_t stream) {
    const float* logits = (const float*)d_in[0];
    const int*   labels = (const int*)d_in[1];
    float* out = (float*)d_out;
    float* ws  = (float*)d_ws;

    hipMemsetAsync(ws, 0, NB * 4 * sizeof(float), stream);
    dice_partial<<<NB * BLOCKS_PER_BATCH, THREADS, 0, stream>>>(logits, labels, ws);
    dice_final<<<1, 64, 0, stream>>>(ws, out);
}